// Round 4
// baseline (72.318 us; speedup 1.0000x reference)
//
#include <hip/hip_runtime.h>
#include <hip/hip_bf16.h>

// Problem constants (fixed by setup_inputs)
#define NG   256   // graphs
#define NPG  64    // nodes per graph
#define INF  128   // in features (K)
#define OUTF 128   // out features (N)
#define NH   16    // heads

// LDS row stride for Wl[nn][k] in bf16 units. 136 bf16 = 68 dwords:
// rows stay 16B-aligned (ds_read_b128 ok); the b128 B-fragment read pattern
// spreads 64 lanes x 4 dwords uniformly at 8 dwords/bank (free 2-way).
#define LDSK 136

typedef __attribute__((ext_vector_type(8))) short bf16x8;  // 8 bf16 = 4 VGPRs
typedef __attribute__((ext_vector_type(4))) float f32x4;   // MFMA accumulator

__device__ __forceinline__ ushort f2bf(float f) {
    union { float f; unsigned int i; } c; c.f = f;
    unsigned int r = c.i + 0x7fffu + ((c.i >> 16) & 1u);  // round-to-nearest-even
    return (ushort)(r >> 16);
}

// Grid 512 = (graph g = bid>>1, column-half c = bid&1). 256 threads = 4 waves.
// 2 blocks/CU -> one block's MFMA phase overlaps the sibling's staging phase.
// Phase 1: stage W[h][k][c*64+nn] -> Wl[nn][k] bf16 (transposed, packed b32).
// Phase 2: wave w computes rows w*16..+15 x cols c*64..+63 via 16 MFMAs.
__global__ __launch_bounds__(256) void mhl_fused_kernel(
    const float* __restrict__ X,     // [NG*NPG][INF] fp32
    const int*   __restrict__ head,  // [NG]
    const float* __restrict__ W,     // [NH][INF][OUTF] fp32
    const float* __restrict__ bias,  // [NH][OUTF] fp32
    float*       __restrict__ Y)     // [NG*NPG][OUTF] fp32
{
    __shared__ ushort Wl[64 * LDSK];  // 64*136*2 = 17408 B

    int bid = (int)blockIdx.x;
    int g   = bid >> 1;
    int c   = bid & 1;          // column half (0 or 1)
    int h   = head[g];
    int t   = (int)threadIdx.x;

    // ---- Phase 1: stage 128k x 64n slice of W[h], transposed, bf16 ----
    // Thread patch: 2 k-rows x 16 n-cols. k-pairs packed into one b32 write.
    // Write banks: (4j + kg) % 32 -> 16 banks x 4 lanes = 4-way (1.58x, cheap).
    {
        int kg  = t >> 2;        // 0..63 -> k0 = 2*kg
        int ng  = t & 3;         // nn0 = ng*16
        int k0  = kg * 2;
        int nn0 = ng * 16;
        const float* s0 = W + h * (INF * OUTF) + k0 * OUTF + c * 64 + nn0;
        const float* s1 = s0 + OUTF;
        unsigned int* dst = (unsigned int*)Wl;
#pragma unroll
        for (int jj = 0; jj < 4; ++jj) {
            float4 v0 = *(const float4*)(s0 + jj * 4);
            float4 v1 = *(const float4*)(s1 + jj * 4);
            int nn = nn0 + jj * 4;
            dst[(nn + 0) * (LDSK / 2) + kg] = (unsigned int)f2bf(v0.x) | ((unsigned int)f2bf(v1.x) << 16);
            dst[(nn + 1) * (LDSK / 2) + kg] = (unsigned int)f2bf(v0.y) | ((unsigned int)f2bf(v1.y) << 16);
            dst[(nn + 2) * (LDSK / 2) + kg] = (unsigned int)f2bf(v0.z) | ((unsigned int)f2bf(v1.z) << 16);
            dst[(nn + 3) * (LDSK / 2) + kg] = (unsigned int)f2bf(v0.w) | ((unsigned int)f2bf(v1.w) << 16);
        }
    }
    __syncthreads();

    // ---- Phase 2: MFMA GEMM (4 waves x 16 rows x 64 cols) ----
    int wave = t >> 6;
    int lane = t & 63;
    int quad = lane >> 4;
    int l16  = lane & 15;
    int mrow = wave * 16;

    // A fragments: A[m=l16][k=quad*8+j], kt tiles of 32 along K
    const float* Xg = X + (g * NPG + mrow + l16) * INF + quad * 8;
    bf16x8 a[4];
#pragma unroll
    for (int kt = 0; kt < 4; ++kt) {
        float v[8] __attribute__((aligned(16)));
        *(float4*)(&v[0]) = *(const float4*)(Xg + kt * 32);
        *(float4*)(&v[4]) = *(const float4*)(Xg + kt * 32 + 4);
#pragma unroll
        for (int j = 0; j < 8; ++j) a[kt][j] = (short)f2bf(v[j]);
    }

    f32x4 acc[4];
#pragma unroll
    for (int nt = 0; nt < 4; ++nt) acc[nt] = (f32x4){0.f, 0.f, 0.f, 0.f};

#pragma unroll
    for (int nt = 0; nt < 4; ++nt) {
        // B fragment: B[k=quad*8+j][n=l16] == Wl[nn][k], k-contiguous in LDS
        const ushort* Wn = &Wl[(nt * 16 + l16) * LDSK + quad * 8];
#pragma unroll
        for (int kt = 0; kt < 4; ++kt) {
            bf16x8 b = *(const bf16x8*)(Wn + kt * 32);
            acc[nt] = __builtin_amdgcn_mfma_f32_16x16x32_bf16(a[kt], b, acc[nt], 0, 0, 0);
        }
    }

    // ---- Epilogue: C/D layout col=lane&15, row=quad*4+reg (m89-verified) ----
    float* Yg = Y + (g * NPG + mrow) * OUTF + c * 64;
#pragma unroll
    for (int nt = 0; nt < 4; ++nt) {
        float bv = bias[h * OUTF + c * 64 + nt * 16 + l16];
#pragma unroll
        for (int r = 0; r < 4; ++r)
            Yg[(quad * 4 + r) * OUTF + nt * 16 + l16] = acc[nt][r] + bv;
    }
}

extern "C" void kernel_launch(void* const* d_in, const int* in_sizes, int n_in,
                              void* d_out, int out_size, void* d_ws, size_t ws_size,
                              hipStream_t stream) {
    // setup_inputs order: inputs, n_node, head, kernel, bias
    const float* X    = (const float*)d_in[0];
    const int*   head = (const int*)d_in[2];
    const float* W    = (const float*)d_in[3];
    const float* bias = (const float*)d_in[4];
    float* Y = (float*)d_out;

    mhl_fused_kernel<<<NG * 2, 256, 0, stream>>>(X, head, W, bias, Y);
}